// Round 3
// baseline (460.929 us; speedup 1.0000x reference)
//
#include <hip/hip_runtime.h>
#include <cstdint>
#include <cstddef>

// Problem constants (fixed by reference: x (4,2048,4096) f32, weight (4096,4096) f32)
#define MDIM 8192
#define NDIM 4096
#define KDIM 4096
#define TERN_THRESH 0.1f

typedef unsigned short u16;
typedef __bf16 bf16x8 __attribute__((ext_vector_type(8)));
typedef float f32x4 __attribute__((ext_vector_type(4)));
typedef u16 u16x4 __attribute__((ext_vector_type(4)));
typedef u16 u16x8 __attribute__((ext_vector_type(8)));

// ---------------------------------------------------------------- helpers ---

__device__ __forceinline__ u16 f2bf(float f) {
  // round-to-nearest-even f32 -> bf16 (inputs are finite, no NaN handling)
  unsigned u = __float_as_uint(f);
  u += 0x7FFFu + ((u >> 16) & 1u);
  return (u16)(u >> 16);
}

__device__ __forceinline__ u16 tern_bf16(float w) {
  // sign(w) * (|w| > 0.1)  as bf16 bits: +1=0x3F80, -1=0xBF80, 0=0
  return w > TERN_THRESH ? (u16)0x3F80u : (w < -TERN_THRESH ? (u16)0xBF80u : (u16)0u);
}

// async global -> LDS, 16 B per lane; LDS side is wave-uniform base + lane*16
__device__ __forceinline__ void load_lds16(const u16* g, u16* s) {
  __builtin_amdgcn_global_load_lds(
      (__attribute__((address_space(1))) void*)(void*)(g),
      (__attribute__((address_space(3))) void*)(void*)(s),
      16, 0, 0);
}

// ------------------------------------------------------- conversion kernel ---
// R3 fix: R0-R2 had lane-stride-32B loads (x4[2i], x4[2i+1]) -> each 16B load
// instruction spanned 2KB and nontemporal defeated partner-line reuse; cvt ran
// at ~1.4 TB/s (212 us) vs 46 us roofline. Now lane-contiguous: thread t loads
// x4[base+t] and x4[base+256+t] (16B lane stride), stores two 8B u16x4 at the
// matching contiguous offsets. Same per-element math -> identical output bytes.

#define XBLOCKS ((MDIM * (size_t)KDIM) / (8 * 256))   // 16384
#define WBLOCKS ((NDIM * (size_t)KDIM) / (8 * 256))   //  8192

__global__ __launch_bounds__(256) void cvt_kernel(const float* __restrict__ x,
                                                  u16* __restrict__ xb,
                                                  const float* __restrict__ w,
                                                  u16* __restrict__ qb) {
  size_t b = blockIdx.x;
  if (b < XBLOCKS) {
    size_t i0 = b * 512 + threadIdx.x;   // f32x4 index, lane-contiguous
    size_t i1 = i0 + 256;
    const f32x4* x4 = (const f32x4*)x;
    f32x4 a = __builtin_nontemporal_load(&x4[i0]);
    f32x4 c = __builtin_nontemporal_load(&x4[i1]);
    u16x4 oa, oc;
    oa[0] = f2bf(a[0]); oa[1] = f2bf(a[1]); oa[2] = f2bf(a[2]); oa[3] = f2bf(a[3]);
    oc[0] = f2bf(c[0]); oc[1] = f2bf(c[1]); oc[2] = f2bf(c[2]); oc[3] = f2bf(c[3]);
    ((u16x4*)xb)[i0] = oa;
    ((u16x4*)xb)[i1] = oc;
  } else {
    size_t i0 = (b - XBLOCKS) * 512 + threadIdx.x;
    size_t i1 = i0 + 256;
    const f32x4* w4 = (const f32x4*)w;
    f32x4 a = __builtin_nontemporal_load(&w4[i0]);
    f32x4 c = __builtin_nontemporal_load(&w4[i1]);
    u16x4 oa, oc;
    oa[0] = tern_bf16(a[0]); oa[1] = tern_bf16(a[1]); oa[2] = tern_bf16(a[2]); oa[3] = tern_bf16(a[3]);
    oc[0] = tern_bf16(c[0]); oc[1] = tern_bf16(c[1]); oc[2] = tern_bf16(c[2]); oc[3] = tern_bf16(c[3]);
    ((u16x4*)qb)[i0] = oa;
    ((u16x4*)qb)[i1] = oc;
  }
}

// ---------------------------------------------------------------- GEMM ------
// R3: 256x256 tile, BK=32, 512 threads = 8 waves (2M x 4N), per-wave output
// 128x64 (8 Mreps x 4 Nreps; 1 MFMA per frag per K-tile). 4-slot LDS ring,
// 3-tile stage lead, ONE barrier per K-tile, register-fragment pipelining:
// LDS reads of the NEXT phase/tile run under the CURRENT MFMA block.
//
// Per tile t (slot S = t&3, ping-pong frag sets cur/nxt):
//   ds_read ab = A Mrep4-7 (slot S)          [4 reads, overlap w/ MFMA 1]
//   STAGE_A(slot S+3, tile t+3)
//   MFMA 16x (a_cur x b_cur -> acc[0..3][*])
//   ds_read a_nxt,b_nxt = A0-3,B of tile t+1 (slot S+1)  [8 reads, overlap w/ MFMA 2]
//   STAGE_B(slot S+3, tile t+3)
//   MFMA 16x (ab x b_cur -> acc[4..7][*])
//   vmcnt(4); barrier
//
// vmcnt ledger: end of tile t drains through tile t+2 (outstanding before
// wait = A,B(t+2)[issued t-1] + A,B(t+3)[issued t] = 8 calls -> vmcnt(4)
// retires A,B(t+2)). Hence slot S+1 (tile t+1) was established at end of
// tile t-1 -> preloading t+1's fragments DURING tile t is legal. In-flight
// never drops below 4 calls; issue->wait distance ~2 tiles (>=2800 cyc).
// Prologue stages tiles 0,1,2 (12 calls), vmcnt(4) retires tiles 0,1.
//
// WAR safety (one barrier/tile): all reads of slot X complete before their
// reader-wave's MFMA use (lgkm), which precedes that wave's end-of-tile
// barrier; the staging that overwrites slot X (tile X+4, issued during tile
// X+1... = after that barrier) can never pass a read. Preload reads of slot
// S+1 issued in tile t complete before end-of-(t+1) barrier; slot S+1 is
// next overwritten by stages issued in tile t+2 -> safe.
// Tail: t+3 >= NTILE stages k=0 into dead slots (never read) to keep the
// ledger uniform. Accumulation order per acc element: tiles ascending, one
// MFMA each -> bit-identical to R2 (absmax preserved).
//
// LDS slot layout (per operand, 16 KB): [256 rows][4 chunks of 16B], linear
// chunk c holds global (row = c>>2, kchunk = (c&3) ^ ((row>>1)&3)). Global
// source pre-swizzled, LDS dest linear (global_load_lds rule), same XOR on
// read -> quad's 16 lanes hit all 8 16B-slots 2x = conflict-free (R1/R2: 0).

#define NTILE (KDIM / 32)   // 128

#define BARRIER() __builtin_amdgcn_s_barrier()
#define FENCE()   asm volatile("" ::: "memory")
#define VMCNT4()  asm volatile("s_waitcnt vmcnt(4)" ::: "memory")

#define MFMA16(AF, BF, I0)                                                   \
  do {                                                                       \
    _Pragma("unroll") for (int _i = 0; _i < 4; ++_i) {                       \
      _Pragma("unroll") for (int _j = 0; _j < 4; ++_j) {                     \
        acc[(I0) + _i][_j] = __builtin_amdgcn_mfma_f32_16x16x32_bf16(        \
            AF[_i], BF[_j], acc[(I0) + _i][_j], 0, 0, 0);                    \
      }                                                                      \
    }                                                                        \
  } while (0)

__global__ __launch_bounds__(512, 2) void gemm_tern_kernel(
    const u16* __restrict__ Xb,     // [MDIM][KDIM] bf16 bits
    const u16* __restrict__ Qb,     // [NDIM][KDIM] bf16 bits
    const float* __restrict__ bias, // [NDIM]
    float* __restrict__ C) {        // [MDIM][NDIM]
  // 4 slots x (A 8192 + B 8192 u16) = 128 KiB
  __shared__ __attribute__((aligned(16))) u16 As[4 * 8192];
  __shared__ __attribute__((aligned(16))) u16 Bs[4 * 8192];

  const int tid  = threadIdx.x;
  const int lane = tid & 63;
  const int wv   = tid >> 6;
  const int wm   = wv >> 2;       // 0..1  (M wave row)
  const int wn   = wv & 3;        // 0..3  (N wave col)
  const int quad = lane >> 4;     // 0..3
  const int l16  = lane & 15;

  // XCD-aware bijective swizzle: 512 wgs, 8 XCDs, 64 contiguous per XCD.
  const int orig    = blockIdx.y * 16 + blockIdx.x;
  const int wg      = (orig & 7) * 64 + (orig >> 3);
  const int rowBase = (wg >> 4) * 256;   // M
  const int colBase = (wg & 15) * 256;   // N

  // Staging: thread covers slot-chunks c = tid and tid+512 (1024 x 16B/slot).
  // Global source pre-swizzled: row = c>>2, kchunk = (c&3) ^ ((row>>1)&3).
  const u16* gA[2];
  const u16* gB[2];
  int sOff[2];
#pragma unroll
  for (int j = 0; j < 2; ++j) {
    int c  = j * 512 + tid;
    int r  = c >> 2;
    int qg = (c & 3) ^ ((r >> 1) & 3);
    gA[j]   = Xb + (size_t)(rowBase + r) * KDIM + qg * 8;
    gB[j]   = Qb + (size_t)(colBase + r) * KDIM + qg * 8;
    sOff[j] = c * 8;  // u16 elements within a slot
  }

#define STAGE_A(s, kt)                                              \
  do {                                                              \
    load_lds16(gA[0] + (kt), (u16*)As + (s) * 8192 + sOff[0]);      \
    load_lds16(gA[1] + (kt), (u16*)As + (s) * 8192 + sOff[1]);      \
  } while (0)
#define STAGE_B(s, kt)                                              \
  do {                                                              \
    load_lds16(gB[0] + (kt), (u16*)Bs + (s) * 8192 + sOff[0]);      \
    load_lds16(gB[1] + (kt), (u16*)Bs + (s) * 8192 + sOff[1]);      \
  } while (0)

  // Fragment LDS element offsets (slot-relative), swizzle-matched.
  int ac[8], bc[4];
#pragma unroll
  for (int i = 0; i < 8; ++i) {
    int r = wm * 128 + i * 16 + l16;
    ac[i] = (r * 4 + (quad ^ ((r >> 1) & 3))) * 8;
  }
#pragma unroll
  for (int j = 0; j < 4; ++j) {
    int r = wn * 64 + j * 16 + l16;
    bc[j] = (r * 4 + (quad ^ ((r >> 1) & 3))) * 8;
  }

#define RD_A(d, i, s) d = *(const bf16x8*)((const u16*)As + (s) * 8192 + ac[i])
#define RD_B(d, j, s) d = *(const bf16x8*)((const u16*)Bs + (s) * 8192 + bc[j])

  f32x4 acc[8][4] = {};
  bf16x8 a0[4], b0[4], a1[4], b1[4], ab[4];

  // Prologue: stage tiles 0,1,2 into slots 0,1,2; retire tiles 0,1.
  STAGE_A(0, 0);  STAGE_B(0, 0);
  STAGE_A(1, 32); STAGE_B(1, 32);
  STAGE_A(2, 64); STAGE_B(2, 64);
  VMCNT4();
  FENCE(); BARRIER(); FENCE();
  // Preload tile 0 fragments (slot 0) into the first ping-pong set.
  RD_A(a0[0], 0, 0); RD_A(a0[1], 1, 0); RD_A(a0[2], 2, 0); RD_A(a0[3], 3, 0);
  RD_B(b0[0], 0, 0); RD_B(b0[1], 1, 0); RD_B(b0[2], 2, 0); RD_B(b0[3], 3, 0);

  // Tile body: S, frag sets, and PRE are compile-time (4x unrolled ring).
#define TILE(S, AC, BC, AN, BN, PRE)                                       \
  do {                                                                     \
    const int kt = (t + 3 < NTILE) ? (t + 3) * 32 : 0;                     \
    RD_A(ab[0], 4, S); RD_A(ab[1], 5, S);                                  \
    RD_A(ab[2], 6, S); RD_A(ab[3], 7, S);                                  \
    STAGE_A(((S) + 3) & 3, kt);                                            \
    __builtin_amdgcn_s_setprio(1);                                         \
    MFMA16(AC, BC, 0);                                                     \
    __builtin_amdgcn_s_setprio(0);                                         \
    if (PRE) {                                                             \
      RD_A(AN[0], 0, ((S) + 1) & 3); RD_A(AN[1], 1, ((S) + 1) & 3);        \
      RD_A(AN[2], 2, ((S) + 1) & 3); RD_A(AN[3], 3, ((S) + 1) & 3);        \
      RD_B(BN[0], 0, ((S) + 1) & 3); RD_B(BN[1], 1, ((S) + 1) & 3);        \
      RD_B(BN[2], 2, ((S) + 1) & 3); RD_B(BN[3], 3, ((S) + 1) & 3);        \
    }                                                                      \
    STAGE_B(((S) + 3) & 3, kt);                                            \
    __builtin_amdgcn_s_setprio(1);                                         \
    MFMA16(ab, BC, 4);                                                     \
    __builtin_amdgcn_s_setprio(0);                                         \
    VMCNT4();                                                              \
    FENCE(); BARRIER(); FENCE();                                           \
    ++t;                                                                   \
  } while (0)

  int t = 0;
  for (int it = 0; it < NTILE / 4 - 1; ++it) {   // 31 iters = tiles 0..123
    TILE(0, a0, b0, a1, b1, 1);
    TILE(1, a1, b1, a0, b0, 1);
    TILE(2, a0, b0, a1, b1, 1);
    TILE(3, a1, b1, a0, b0, 1);
  }
  TILE(0, a0, b0, a1, b1, 1);   // t = 124
  TILE(1, a1, b1, a0, b0, 1);   // t = 125
  TILE(2, a0, b0, a1, b1, 1);   // t = 126  (preloads tile 127, slot 3)
  TILE(3, a1, b1, a0, b0, 0);   // t = 127  (no preload)

  // Epilogue: C/D layout col = lane&15, row = quad*4 + reg (verified)
  float bv[4];
#pragma unroll
  for (int j = 0; j < 4; ++j) bv[j] = bias[colBase + wn * 64 + j * 16 + l16];

#pragma unroll
  for (int i = 0; i < 8; ++i) {
#pragma unroll
    for (int r = 0; r < 4; ++r) {
      int grow = rowBase + wm * 128 + i * 16 + quad * 4 + r;
      float* crow = C + (size_t)grow * NDIM + colBase + wn * 64 + l16;
#pragma unroll
      for (int j = 0; j < 4; ++j) {
        crow[j * 16] = acc[i][j][r] + bv[j];
      }
    }
  }
}

// ---------------------------------------------------------------- launch ----

extern "C" void kernel_launch(void* const* d_in, const int* in_sizes, int n_in,
                              void* d_out, int out_size, void* d_ws, size_t ws_size,
                              hipStream_t stream) {
  const float* x    = (const float*)d_in[0];
  const float* w    = (const float*)d_in[1];
  const float* bias = (const float*)d_in[2];
  float* out = (float*)d_out;

  // workspace: Xb bf16 [MDIM*KDIM] then Qb bf16 [NDIM*KDIM]  (= 100.7 MB)
  u16* xb = (u16*)d_ws;
  u16* qb = xb + (size_t)MDIM * KDIM;

  cvt_kernel<<<(unsigned)(XBLOCKS + WBLOCKS), 256, 0, stream>>>(x, xb, w, qb);

  dim3 grid(NDIM / 256, MDIM / 256);   // (16, 32)
  gemm_tern_kernel<<<grid, 512, 0, stream>>>(xb, qb, bias, out);
}